// Round 9
// baseline (1597.184 us; speedup 1.0000x reference)
//
#include <hip/hip_runtime.h>
#include <hip/hip_cooperative_groups.h>
#include <math.h>

namespace cg = cooperative_groups;

typedef unsigned short ushort_t;
typedef unsigned int uint_t;
typedef unsigned long long ull_t;

#define NREP 16
#define MGRID 512   // 2 blocks/CU guaranteed co-resident (LDS ~42KB/block, VGPR<=256)

__device__ __forceinline__ float bf2f(ushort_t u) {
    union { uint_t i; float f; } x; x.i = ((uint_t)u) << 16; return x.f;
}
__device__ __forceinline__ ushort_t f2bf(float f) {
    union { float f; uint_t i; } x; x.f = f;
    uint_t r = x.i + 0x7FFFu + ((x.i >> 16) & 1u);
    return (ushort_t)(r >> 16);
}

// =============== shared device bodies (used by mega + serial fallback) ===============

// one 64x64 GEMM tile. PREP: fold BN(stats)+W into LDS B-panel + per-tile wbias.
template<int KP, bool F32A, bool PREP>
__device__ __forceinline__ void gemm_tile(
    int bx, int by, const void* __restrict__ Xin, const ushort_t* __restrict__ Wt,
    const float* __restrict__ Wf, const float* __restrict__ g,
    const float* __restrict__ be, const float* __restrict__ sp,
    const float* __restrict__ dinv, ushort_t* __restrict__ h2,
    int N, int Mp, int K, int M, float invN,
    ushort_t* Bs, float* sm_sc, float* sm_off, float (*red)[64], float* wb_l)
{
    typedef __attribute__((ext_vector_type(8))) short short8;
    typedef __attribute__((ext_vector_type(4))) float floatx4;
    constexpr int LSTR = KP + 16;
    const int tid = threadIdx.x;
    const int wave = tid >> 6, lane = tid & 63;
    const int m = lane & 15, quad = lane >> 4;
    const int i0 = bx * 64 + wave * 16;
    const int j0 = by * 64;
    const int ncols = min(64, Mp - j0);
    const int ntiles = ncols >> 4;

    if (PREP) {
        {   // BN finalize from replicated stats
            const int kk = tid;
            float sc = 0.f, off = 0.f;
            if (kk < K) {
                float ssum = 0.f, qsum = 0.f;
                #pragma unroll
                for (int r = 0; r < NREP; ++r) {
                    ssum += sp[r * 512 + kk];
                    qsum += sp[r * 512 + 256 + kk];
                }
                float mu = ssum * invN;
                float var = qsum * invN - mu * mu;
                sc = g[kk] * rsqrtf(var + 1e-5f);
                off = be[kk] - mu * sc;
            }
            sm_sc[kk] = sc; sm_off[kk] = off;
        }
        __syncthreads();
        {   // fold B panel + wbias partials
            const int jj = tid & 63, kg = tid >> 6;
            const int j = j0 + jj;
            float wpart = 0.f;
            for (int kk = kg; kk < KP; kk += 4) {
                float wv = (kk < K && j < M) ? Wf[(long)kk * M + j] : 0.f;
                Bs[jj * LSTR + kk] = f2bf(sm_sc[kk] * wv);
                wpart += sm_off[kk] * wv;
            }
            red[kg][jj] = wpart;
        }
        __syncthreads();
        if (tid < 64) wb_l[tid] = red[0][tid] + red[1][tid] + red[2][tid] + red[3][tid];
        __syncthreads();
    } else {
        const int cpr = KP / 8;
        const int chunks = ncols * cpr;
        for (int c = tid; c < chunks; c += 256) {
            int jj = c / cpr;
            int kk = (c - jj * cpr) * 8;
            *(short8*)(Bs + jj * LSTR + kk) =
                *(const short8*)(Wt + (long)(j0 + jj) * KP + kk);
        }
        __syncthreads();
    }

    if (i0 < N) {
        floatx4 acc[4];
        #pragma unroll
        for (int t = 0; t < 4; ++t) { acc[t].x = 0.f; acc[t].y = 0.f; acc[t].z = 0.f; acc[t].w = 0.f; }

        const int ra = min(i0 + m, N - 1);
        const ushort_t* arow_h = F32A ? nullptr : (const ushort_t*)Xin + (long)ra * KP + quad * 8;
        const float*    arow_f = F32A ? (const float*)Xin + (long)ra * KP + quad * 8 : nullptr;

        #pragma unroll
        for (int k0 = 0; k0 < KP; k0 += 32) {
            short8 av;
            if (F32A) {
                float4 f0 = *(const float4*)(arow_f + k0);
                float4 f1 = *(const float4*)(arow_f + k0 + 4);
                av[0] = (short)f2bf(f0.x); av[1] = (short)f2bf(f0.y);
                av[2] = (short)f2bf(f0.z); av[3] = (short)f2bf(f0.w);
                av[4] = (short)f2bf(f1.x); av[5] = (short)f2bf(f1.y);
                av[6] = (short)f2bf(f1.z); av[7] = (short)f2bf(f1.w);
            } else {
                av = *(const short8*)(arow_h + k0);
            }
            #pragma unroll
            for (int t = 0; t < 4; ++t) {
                if (t < ntiles) {
                    short8 bv = *(const short8*)(Bs + (t * 16 + m) * LSTR + k0 + quad * 8);
                    acc[t] = __builtin_amdgcn_mfma_f32_16x16x32_bf16(av, bv, acc[t], 0, 0, 0);
                }
            }
        }

        #pragma unroll
        for (int t = 0; t < 4; ++t) {
            if (t < ntiles) {
                int j = j0 + t * 16 + m;
                float wb = PREP ? wb_l[t * 16 + m] : 0.0f;   // layer-0 wbias == 0
                #pragma unroll
                for (int r = 0; r < 4; ++r) {
                    int i = i0 + quad * 4 + r;
                    if (i < N) h2[(long)i * Mp + j] = f2bf((acc[t][r] + wb) * dinv[i]);
                }
            }
        }
    }
    __syncthreads();   // protect Bs/wb_l before this block restages next tile
}

// one agg block: 256 threads, 8 cols x 8-deep-pipelined gather, fused BN stats.
__device__ __forceinline__ void agg_tile(
    int vb, const int* __restrict__ row_start, const int* __restrict__ csr_src,
    const ushort_t* __restrict__ h2, int hs,
    const float* __restrict__ dinv, const float* __restrict__ b,
    ushort_t* __restrict__ tmpb, int ts, float* __restrict__ sp,
    int N, int M, int Q, float* s_s, float* s_q)
{
    const int tid = threadIdx.x;
    s_s[tid] = 0.f; s_q[tid] = 0.f;
    __syncthreads();

    const uint_t g = (uint_t)vb * 256u + (uint_t)tid;
    const uint_t i = g / (uint_t)Q;
    const int jp = (int)(g - i * (uint_t)Q);
    const int j0 = jp * 8;
    float vals[8];
    bool active = false;

    if (i < (uint_t)N) {
        if (j0 >= M) {
            *(uint4*)(tmpb + (long)i * ts + j0) = make_uint4(0u, 0u, 0u, 0u);
        } else {
            active = true;
            const int s0 = row_start[i];
            const int s1 = row_start[i + 1];
            const ushort_t* hp = h2 + j0;
            float acc[8];
            {
                uint4 v = *(const uint4*)(hp + (long)i * hs);
                acc[0] = bf2f((ushort_t)(v.x & 0xffff)); acc[1] = bf2f((ushort_t)(v.x >> 16));
                acc[2] = bf2f((ushort_t)(v.y & 0xffff)); acc[3] = bf2f((ushort_t)(v.y >> 16));
                acc[4] = bf2f((ushort_t)(v.z & 0xffff)); acc[5] = bf2f((ushort_t)(v.z >> 16));
                acc[6] = bf2f((ushort_t)(v.w & 0xffff)); acc[7] = bf2f((ushort_t)(v.w >> 16));
            }
            int e = s0;
            for (; e + 7 < s1; e += 8) {
                uint4 w[8];
                #pragma unroll
                for (int u = 0; u < 8; ++u)
                    w[u] = *(const uint4*)(hp + (long)csr_src[e + u] * hs);
                #pragma unroll
                for (int u = 0; u < 8; ++u) {
                    acc[0] += bf2f((ushort_t)(w[u].x & 0xffff)); acc[1] += bf2f((ushort_t)(w[u].x >> 16));
                    acc[2] += bf2f((ushort_t)(w[u].y & 0xffff)); acc[3] += bf2f((ushort_t)(w[u].y >> 16));
                    acc[4] += bf2f((ushort_t)(w[u].z & 0xffff)); acc[5] += bf2f((ushort_t)(w[u].z >> 16));
                    acc[6] += bf2f((ushort_t)(w[u].w & 0xffff)); acc[7] += bf2f((ushort_t)(w[u].w >> 16));
                }
            }
            if (e + 3 < s1) {
                uint4 w[4];
                #pragma unroll
                for (int u = 0; u < 4; ++u)
                    w[u] = *(const uint4*)(hp + (long)csr_src[e + u] * hs);
                #pragma unroll
                for (int u = 0; u < 4; ++u) {
                    acc[0] += bf2f((ushort_t)(w[u].x & 0xffff)); acc[1] += bf2f((ushort_t)(w[u].x >> 16));
                    acc[2] += bf2f((ushort_t)(w[u].y & 0xffff)); acc[3] += bf2f((ushort_t)(w[u].y >> 16));
                    acc[4] += bf2f((ushort_t)(w[u].z & 0xffff)); acc[5] += bf2f((ushort_t)(w[u].z >> 16));
                    acc[6] += bf2f((ushort_t)(w[u].w & 0xffff)); acc[7] += bf2f((ushort_t)(w[u].w >> 16));
                }
                e += 4;
            }
            for (; e < s1; ++e) {
                uint4 w = *(const uint4*)(hp + (long)csr_src[e] * hs);
                acc[0] += bf2f((ushort_t)(w.x & 0xffff)); acc[1] += bf2f((ushort_t)(w.x >> 16));
                acc[2] += bf2f((ushort_t)(w.y & 0xffff)); acc[3] += bf2f((ushort_t)(w.y >> 16));
                acc[4] += bf2f((ushort_t)(w.z & 0xffff)); acc[5] += bf2f((ushort_t)(w.z >> 16));
                acc[6] += bf2f((ushort_t)(w.w & 0xffff)); acc[7] += bf2f((ushort_t)(w.w >> 16));
            }
            const float di = dinv[i];
            ushort_t r[8];
            #pragma unroll
            for (int u = 0; u < 8; ++u) {
                float v = (j0 + u < M) ? fmaxf(acc[u] * di + b[j0 + u], 0.f) : 0.f;
                vals[u] = v;
                r[u] = f2bf(v);
            }
            uint4 pk;
            pk.x = (uint_t)r[0] | ((uint_t)r[1] << 16);
            pk.y = (uint_t)r[2] | ((uint_t)r[3] << 16);
            pk.z = (uint_t)r[4] | ((uint_t)r[5] << 16);
            pk.w = (uint_t)r[6] | ((uint_t)r[7] << 16);
            *(uint4*)(tmpb + (long)i * ts + j0) = pk;
        }
    }

    if (active) {
        #pragma unroll
        for (int u = 0; u < 8; ++u) {
            atomicAdd(&s_s[j0 + u], vals[u]);
            atomicAdd(&s_q[j0 + u], vals[u] * vals[u]);
        }
    }
    __syncthreads();
    float* rep = sp + (vb & (NREP - 1)) * 512;
    if (tid < ts && (s_s[tid] != 0.f || s_q[tid] != 0.f)) {
        unsafeAtomicAdd(&rep[tid], s_s[tid]);
        unsafeAtomicAdd(&rep[tid + 256], s_q[tid]);
    }
}

// one final-layer block: 16 rows x 16 col-pairs, gather + bias + log_softmax.
__device__ __forceinline__ void final_tile(
    int vb, const int* __restrict__ row_start, const int* __restrict__ csr_src,
    const ushort_t* __restrict__ h2, const float* __restrict__ dinv,
    const float* __restrict__ b, float* __restrict__ out, int N, int M)
{
    const int tid = threadIdx.x;
    const int x = tid & 15;
    const int r = tid >> 4;
    const int i = vb * 16 + r;
    const bool act = (i < N);
    const int ii = act ? i : (N - 1);
    const int j0 = 2 * x, j1 = j0 + 1;
    uint_t v = *(const uint_t*)(h2 + (long)ii * 32 + j0);
    float a0 = bf2f((ushort_t)(v & 0xffff));
    float a1 = bf2f((ushort_t)(v >> 16));
    const int s0 = row_start[ii];
    const int s1 = row_start[ii + 1];
    int e = s0;
    for (; e + 3 < s1; e += 4) {
        uint_t w[4];
        #pragma unroll
        for (int u = 0; u < 4; ++u)
            w[u] = *(const uint_t*)(h2 + (long)csr_src[e + u] * 32 + j0);
        #pragma unroll
        for (int u = 0; u < 4; ++u) {
            a0 += bf2f((ushort_t)(w[u] & 0xffff));
            a1 += bf2f((ushort_t)(w[u] >> 16));
        }
    }
    for (; e < s1; ++e) {
        uint_t w = *(const uint_t*)(h2 + (long)csr_src[e] * 32 + j0);
        a0 += bf2f((ushort_t)(w & 0xffff)); a1 += bf2f((ushort_t)(w >> 16));
    }
    const float di = dinv[ii];
    float r0 = (j0 < M) ? (a0 * di + b[j0]) : -INFINITY;
    float r1 = (j1 < M) ? (a1 * di + b[j1]) : -INFINITY;
    float m = fmaxf(r0, r1);
    #pragma unroll
    for (int msk = 1; msk < 16; msk <<= 1) m = fmaxf(m, __shfl_xor(m, msk, 16));
    float s = ((j0 < M) ? expf(r0 - m) : 0.f) + ((j1 < M) ? expf(r1 - m) : 0.f);
    #pragma unroll
    for (int msk = 1; msk < 16; msk <<= 1) s += __shfl_xor(s, msk, 16);
    const float l = logf(s) + m;
    if (act) {
        if (j0 < M) out[(long)i * M + j0] = r0 - l;
        if (j1 < M) out[(long)i * M + j1] = r1 - l;
    }
}

// =============== persistent cooperative mega-kernel ===============

struct MegaP {
    const float* x;
    const int* srcv; const int* dstv;
    const float* W[5]; const float* b[5];
    const float* g[4]; const float* be[4];
    float* out;
    float* dinv; float* stats;
    int* cnt; int* row_start; int* cursor; int* csr_src; int* bpart;
    ushort_t* Wt; ushort_t* h2; ushort_t* tmpb;
    int N, E;
};

__global__ __launch_bounds__(256, 2) void k_mega(MegaP P)
{
    cg::grid_group gr = cg::this_grid();
    __shared__ ushort_t Bs[64 * 272];
    __shared__ float s_s[256], s_q[256];
    __shared__ float sm_sc[256], sm_off[256];
    __shared__ float red[4][64];
    __shared__ float wb_l[64];
    __shared__ int sh_i[256];

    const int tid = threadIdx.x;
    const int bid = blockIdx.x;
    const int nb = gridDim.x;
    const int gt0 = bid * 256 + tid;
    const int gstep = nb * 256;
    const float invN = 1.0f / (float)P.N;

    // P0: zero cnt + stats
    for (int i = gt0; i < P.N; i += gstep) P.cnt[i] = 0;
    for (int i = gt0; i < 4 * NREP * 512; i += gstep) P.stats[i] = 0.f;
    __threadfence();
    gr.sync();

    // P1: degree histogram + layer-0 Wt fold
    for (int e = gt0; e < P.E; e += gstep) atomicAdd(&P.cnt[P.dstv[e]], 1);
    for (int idx = gt0; idx < 224 * 256; idx += gstep) {
        int j = idx >> 8, k = idx & 255;
        P.Wt[idx] = f2bf((j < 220) ? P.W[0][(long)k * 220 + j] : 0.f);
    }
    __threadfence();
    gr.sync();

    // P2a: per-256-row block sums
    const int nsb = (P.N + 255) >> 8;
    for (int sb = bid; sb < nsb; sb += nb) {
        int i = sb * 256 + tid;
        sh_i[tid] = (i < P.N) ? P.cnt[i] : 0;
        __syncthreads();
        for (int off = 128; off > 0; off >>= 1) {
            if (tid < off) sh_i[tid] += sh_i[tid + off];
            __syncthreads();
        }
        if (tid == 0) P.bpart[sb] = sh_i[0];
        __syncthreads();
    }
    __threadfence();
    gr.sync();

    // P2b: scan + write row_start/cursor/dinv
    for (int sb = bid; sb < nsb; sb += nb) {
        int base = 0;
        for (int k2 = 0; k2 < sb; ++k2) base += P.bpart[k2];
        int i = sb * 256 + tid;
        int v = (i < P.N) ? P.cnt[i] : 0;
        sh_i[tid] = v;
        __syncthreads();
        for (int off = 1; off < 256; off <<= 1) {
            int t2 = (tid >= off) ? sh_i[tid - off] : 0;
            __syncthreads();
            sh_i[tid] += t2;
            __syncthreads();
        }
        int incl = sh_i[tid], excl = incl - v;
        if (i < P.N) {
            int rs = base + excl;
            P.row_start[i] = rs;
            P.cursor[i] = rs;
            P.dinv[i] = rsqrtf(1.0f + (float)v);
            if (i == P.N - 1) P.row_start[P.N] = base + incl;
        }
        __syncthreads();
    }
    __threadfence();
    gr.sync();

    // layers
    const int dims[6] = {256, 220, 150, 100, 60, 17};
    for (int l = 0; l < 5; ++l) {
        const int K = dims[l], M = dims[l + 1];
        const int Mp = (M + 15) & ~15;
        const int ts = (l < 4) ? ((M + 31) & ~31) : 32;
        const int gx = (P.N + 63) >> 6, gy = (Mp + 63) >> 6;
        const int Lg = gx * gy;
        const int Lf = (l == 0) ? ((P.E + 255) >> 8) : 0;
        const float* spv = (l > 0) ? (P.stats + (long)(l - 1) * NREP * 512) : nullptr;

        for (int vb = bid; vb < Lg + Lf; vb += nb) {
            if (vb >= Lg) {          // CSR fill rides along with gemm0
                int e = (vb - Lg) * 256 + tid;
                if (e < P.E) {
                    int pos = atomicAdd(&P.cursor[P.dstv[e]], 1);
                    P.csr_src[pos] = P.srcv[e];
                }
            } else {
                int bx = vb % gx, by = vb / gx;
                if (l == 0)
                    gemm_tile<256, true, false>(bx, by, P.x, P.Wt, nullptr, nullptr, nullptr, nullptr,
                        P.dinv, P.h2, P.N, Mp, K, M, invN, Bs, sm_sc, sm_off, red, wb_l);
                else if (l == 1)
                    gemm_tile<224, false, true>(bx, by, P.tmpb, nullptr, P.W[1], P.g[0], P.be[0], spv,
                        P.dinv, P.h2, P.N, Mp, K, M, invN, Bs, sm_sc, sm_off, red, wb_l);
                else if (l == 2)
                    gemm_tile<160, false, true>(bx, by, P.tmpb, nullptr, P.W[2], P.g[1], P.be[1], spv,
                        P.dinv, P.h2, P.N, Mp, K, M, invN, Bs, sm_sc, sm_off, red, wb_l);
                else if (l == 3)
                    gemm_tile<128, false, true>(bx, by, P.tmpb, nullptr, P.W[3], P.g[2], P.be[2], spv,
                        P.dinv, P.h2, P.N, Mp, K, M, invN, Bs, sm_sc, sm_off, red, wb_l);
                else
                    gemm_tile<64, false, true>(bx, by, P.tmpb, nullptr, P.W[4], P.g[3], P.be[3], spv,
                        P.dinv, P.h2, P.N, Mp, K, M, invN, Bs, sm_sc, sm_off, red, wb_l);
            }
        }
        __threadfence();
        gr.sync();

        if (l < 4) {
            const int Q = ts >> 3;
            const int Lq = (int)(((long)P.N * Q + 255) >> 8);
            for (int vb = bid; vb < Lq; vb += nb)
                agg_tile(vb, P.row_start, P.csr_src, P.h2, Mp, P.dinv, P.b[l],
                         P.tmpb, ts, P.stats + (long)l * NREP * 512, P.N, M, Q, s_s, s_q);
            __threadfence();
            gr.sync();
        } else {
            const int Lq = (P.N + 15) >> 4;
            for (int vb = bid; vb < Lq; vb += nb)
                final_tile(vb, P.row_start, P.csr_src, P.h2, P.dinv, P.b[4], P.out, P.N, M);
        }
    }
}

// =============== serial fallback kernels (R7 behavior via shared bodies) ===============

__global__ __launch_bounds__(256) void k_init(
    int* __restrict__ cnt, float* __restrict__ stats, int N)
{
    const int gt = blockIdx.x * 256 + threadIdx.x;
    const int gth = gridDim.x * 256;
    for (int i = gt; i < N; i += gth) cnt[i] = 0;
    for (int i = gt; i < 4 * NREP * 512; i += gth) stats[i] = 0.f;
}

__global__ __launch_bounds__(256) void k_hist_prep0(
    const int* __restrict__ dst, int* __restrict__ cnt, int E, int eBlk,
    const float* __restrict__ W0, ushort_t* __restrict__ Wt)
{
    if ((int)blockIdx.x < eBlk) {
        int e = blockIdx.x * 256 + threadIdx.x;
        if (e < E) atomicAdd(&cnt[dst[e]], 1);
    } else {
        int base = ((int)blockIdx.x - eBlk) * 256 + (int)threadIdx.x;
        for (int idx = base; idx < 224 * 256; idx += 56 * 256) {
            int j = idx >> 8;
            int k = idx & 255;
            Wt[idx] = f2bf((j < 220) ? W0[(long)k * 220 + j] : 0.f);
        }
    }
}

__global__ __launch_bounds__(1024) void k_scan(
    const int* __restrict__ cnt, int* __restrict__ row_start,
    int* __restrict__ cursor, float* __restrict__ dinv, int N)
{
    __shared__ int sh[1024];
    const int tid = threadIdx.x;
    const int chunk = (N + 1023) >> 10;
    int loc[16];
    const int base = tid * chunk;
    int sum = 0;
    for (int c = 0; c < chunk; ++c) {
        int i = base + c;
        int v = (i < N) ? cnt[i] : 0;
        loc[c] = sum;
        sum += v;
    }
    sh[tid] = sum;
    __syncthreads();
    for (int off = 1; off < 1024; off <<= 1) {
        int v = (tid >= off) ? sh[tid - off] : 0;
        __syncthreads();
        sh[tid] += v;
        __syncthreads();
    }
    const int excl = sh[tid] - sum;
    for (int c = 0; c < chunk; ++c) {
        int i = base + c;
        if (i < N) {
            int rs = excl + loc[c];
            row_start[i] = rs;
            cursor[i] = rs;
            dinv[i] = rsqrtf(1.0f + (float)cnt[i]);
        }
    }
    if (tid == 1023) row_start[N] = sh[1023];
}

template<int KP, bool F32A, bool FILL, bool PREP>
__global__ __launch_bounds__(256) void k_gemm(
    const void* __restrict__ Xin, const ushort_t* __restrict__ Wt,
    const float* __restrict__ Wf, const float* __restrict__ g,
    const float* __restrict__ be, const float* __restrict__ sp,
    const float* __restrict__ dinv, ushort_t* __restrict__ h2,
    int N, int Mp, int K, int M, float invN,
    int gx, const int* __restrict__ fsrc, const int* __restrict__ fdst,
    int* __restrict__ fcursor, int* __restrict__ fcsr, int fE)
{
    __shared__ ushort_t Bs[64 * (KP + 16)];
    __shared__ float sm_sc[256], sm_off[256];
    __shared__ float red[4][64];
    __shared__ float wb_l[64];
    if (FILL) {
        if ((int)blockIdx.x >= gx) {
            const int fid = ((int)blockIdx.x - gx) * (int)gridDim.y + (int)blockIdx.y;
            const int e = fid * 256 + (int)threadIdx.x;
            if (e < fE) {
                int pos = atomicAdd(&fcursor[fdst[e]], 1);
                fcsr[pos] = fsrc[e];
            }
            return;
        }
    }
    gemm_tile<KP, F32A, PREP>(blockIdx.x, blockIdx.y, Xin, Wt, Wf, g, be, sp,
                              dinv, h2, N, Mp, K, M, invN, Bs, sm_sc, sm_off, red, wb_l);
}

__global__ __launch_bounds__(256) void k_agg(
    const int* __restrict__ row_start, const int* __restrict__ csr_src,
    const ushort_t* __restrict__ h2, int hs,
    const float* __restrict__ dinv, const float* __restrict__ b,
    ushort_t* __restrict__ tmpb, int ts, float* __restrict__ sp,
    int N, int M, int Q)
{
    __shared__ float s_s[256], s_q[256];
    agg_tile(blockIdx.x, row_start, csr_src, h2, hs, dinv, b, tmpb, ts, sp, N, M, Q, s_s, s_q);
}

__global__ __launch_bounds__(256) void k_agg_final(
    const int* __restrict__ row_start, const int* __restrict__ csr_src,
    const ushort_t* __restrict__ h2, const float* __restrict__ dinv,
    const float* __restrict__ b, float* __restrict__ out, int N, int M)
{
    final_tile(blockIdx.x, row_start, csr_src, h2, dinv, b, out, N, M);
}

// =============== launch ===============

static inline int pad16(int v) { return (v + 15) & ~15; }
static inline int pad32(int v) { return (v + 31) & ~31; }

extern "C" void kernel_launch(void* const* d_in, const int* in_sizes, int n_in,
                              void* d_out, int out_size, void* d_ws, size_t ws_size,
                              hipStream_t stream)
{
    const int dims[6] = {256, 220, 150, 100, 60, 17};
    const int N = in_sizes[0] / dims[0];      // 10000
    const int E = in_sizes[1] / 2;            // 320000

    const float* x  = (const float*)d_in[0];
    const int* ei   = (const int*)d_in[1];
    const int* srcv = ei;
    const int* dstv = ei + E;
    const float* Wl[5], *bl[5];
    for (int l = 0; l < 5; ++l) {
        Wl[l] = (const float*)d_in[2 + 2 * l];
        bl[l] = (const float*)d_in[3 + 2 * l];
    }
    const float* gl[4], *bel[4];
    for (int l = 0; l < 4; ++l) {
        gl[l]  = (const float*)d_in[12 + 2 * l];
        bel[l] = (const float*)d_in[13 + 2 * l];
    }
    float* out = (float*)d_out;

    // ---- workspace layout ----
    char* w = (char*)d_ws;
    const long NB  = ((long)N * 4 + 255) & ~255L;
    const long NB1 = ((long)(N + 1) * 4 + 255) & ~255L;
    const long EB  = ((long)E * 4 + 255) & ~255L;
    const long FBB = ((long)N * 224 * 2 + 255) & ~255L;
    const long WTB = ((long)224 * 256 * 2 + 255) & ~255L;
    const long STB = (long)4 * NREP * 512 * 4;

    long o = 0;
    float* dinv      = (float*)(w + o);  o += NB;
    float* stats     = (float*)(w + o);  o += STB;
    int*   bpart     = (int*)(w + o);    o += 2048;
    int*   cnt       = (int*)(w + o);    o += NB;
    int*   row_start = (int*)(w + o);    o += NB1;
    int*   cursor    = (int*)(w + o);    o += NB;
    int*   csr_src   = (int*)(w + o);    o += EB;
    ushort_t* Wt     = (ushort_t*)(w + o); o += WTB;
    ushort_t* h2     = (ushort_t*)(w + o); o += FBB;
    ushort_t* tmpb   = (ushort_t*)(w + o); o += FBB;

    // ---- try the persistent cooperative mega-kernel ----
    MegaP mp;
    mp.x = x; mp.srcv = srcv; mp.dstv = dstv;
    for (int l = 0; l < 5; ++l) { mp.W[l] = Wl[l]; mp.b[l] = bl[l]; }
    for (int l = 0; l < 4; ++l) { mp.g[l] = gl[l]; mp.be[l] = bel[l]; }
    mp.out = out;
    mp.dinv = dinv; mp.stats = stats;
    mp.cnt = cnt; mp.row_start = row_start; mp.cursor = cursor;
    mp.csr_src = csr_src; mp.bpart = bpart;
    mp.Wt = Wt; mp.h2 = h2; mp.tmpb = tmpb;
    mp.N = N; mp.E = E;

    void* args[] = { (void*)&mp };
    hipError_t rc = hipLaunchCooperativeKernel((void*)k_mega, dim3(MGRID), dim3(256),
                                               args, 0, stream);
    if (rc == hipSuccess) return;
    (void)hipGetLastError();   // clear sticky error, fall back to serial path

    // ---- serial fallback (R7 structure) ----
    const int eBlk = (E + 255) / 256;
    const float invN = 1.0f / (float)N;

    k_init<<<(N + 255) / 256, 256, 0, stream>>>(cnt, stats, N);
    k_hist_prep0<<<eBlk + 56, 256, 0, stream>>>(dstv, cnt, E, eBlk, Wl[0], Wt);
    k_scan<<<1, 1024, 0, stream>>>(cnt, row_start, cursor, dinv, N);

    for (int l = 0; l < 5; ++l) {
        const int K  = dims[l];
        const int M  = dims[l + 1];
        const int Kp = pad32(K);
        const int Mp = pad16(M);
        const int ts = (l < 4) ? pad32(M) : 32;

        dim3 gg((N + 63) / 64, (Mp + 63) / 64);
        if (l == 0) {
            const int fx = (eBlk + (int)gg.y - 1) / (int)gg.y;
            dim3 gg0(gg.x + fx, gg.y);
            k_gemm<256, true, true, false><<<gg0, 256, 0, stream>>>(
                x, Wt, nullptr, nullptr, nullptr, nullptr,
                dinv, h2, N, Mp, K, M, invN,
                (int)gg.x, srcv, dstv, cursor, csr_src, E);
        } else {
            const float* sp = stats + (long)(l - 1) * NREP * 512;
            switch (Kp) {
                case 224: k_gemm<224, false, false, true><<<gg, 256, 0, stream>>>(
                    tmpb, nullptr, Wl[l], gl[l - 1], bel[l - 1], sp,
                    dinv, h2, N, Mp, K, M, invN, 0, nullptr, nullptr, nullptr, nullptr, 0); break;
                case 160: k_gemm<160, false, false, true><<<gg, 256, 0, stream>>>(
                    tmpb, nullptr, Wl[l], gl[l - 1], bel[l - 1], sp,
                    dinv, h2, N, Mp, K, M, invN, 0, nullptr, nullptr, nullptr, nullptr, 0); break;
                case 128: k_gemm<128, false, false, true><<<gg, 256, 0, stream>>>(
                    tmpb, nullptr, Wl[l], gl[l - 1], bel[l - 1], sp,
                    dinv, h2, N, Mp, K, M, invN, 0, nullptr, nullptr, nullptr, nullptr, 0); break;
                case  64: k_gemm< 64, false, false, true><<<gg, 256, 0, stream>>>(
                    tmpb, nullptr, Wl[l], gl[l - 1], bel[l - 1], sp,
                    dinv, h2, N, Mp, K, M, invN, 0, nullptr, nullptr, nullptr, nullptr, 0); break;
            }
        }

        if (l < 4) {
            const int Q = ts / 8;
            const long total = (long)N * Q;
            k_agg<<<(int)((total + 255) / 256), 256, 0, stream>>>(
                row_start, csr_src, h2, Mp, dinv, bl[l], tmpb, ts,
                stats + (long)l * NREP * 512, N, M, Q);
        } else {
            k_agg_final<<<(N + 15) / 16, 256, 0, stream>>>(
                row_start, csr_src, h2, dinv, bl[l], out, N, M);
        }
    }
}

// Round 10
// 354.427 us; speedup vs baseline: 4.5064x; 4.5064x over previous
//
#include <hip/hip_runtime.h>
#include <math.h>

typedef unsigned short ushort_t;
typedef unsigned int uint_t;
typedef unsigned long long ull_t;

#define NREP 16
#define IDXCAP 4608    // ints of LDS-staged csr indices per k_agg block (mean ~1056 worst layer)
#define FIDXCAP 2048   // final layer (mean ~512)

__device__ __forceinline__ float bf2f(ushort_t u) {
    union { uint_t i; float f; } x; x.i = ((uint_t)u) << 16; return x.f;
}
__device__ __forceinline__ ushort_t f2bf(float f) {
    union { float f; uint_t i; } x; x.f = f;
    uint_t r = x.i + 0x7FFFu + ((x.i >> 16) & 1u);
    return (ushort_t)(r >> 16);
}

// ---------------- init ----------------
__global__ __launch_bounds__(256) void k_init(
    int* __restrict__ cnt, float* __restrict__ stats, int N)
{
    const int gt = blockIdx.x * 256 + threadIdx.x;
    const int gth = gridDim.x * 256;
    for (int i = gt; i < N; i += gth) cnt[i] = 0;
    for (int i = gt; i < 4 * NREP * 512; i += gth) stats[i] = 0.f;
}

// hist + prep0 fused
__global__ __launch_bounds__(256) void k_hist_prep0(
    const int* __restrict__ dst, int* __restrict__ cnt, int E, int eBlk,
    const float* __restrict__ W0, ushort_t* __restrict__ Wt)
{
    if ((int)blockIdx.x < eBlk) {
        int e = blockIdx.x * 256 + threadIdx.x;
        if (e < E) atomicAdd(&cnt[dst[e]], 1);
    } else {
        int base = ((int)blockIdx.x - eBlk) * 256 + (int)threadIdx.x;
        for (int idx = base; idx < 224 * 256; idx += 56 * 256) {
            int j = idx >> 8;
            int k = idx & 255;
            Wt[idx] = f2bf((j < 220) ? W0[(long)k * 220 + j] : 0.f);
        }
    }
}

__global__ __launch_bounds__(1024) void k_scan(
    const int* __restrict__ cnt, int* __restrict__ row_start,
    int* __restrict__ cursor, float* __restrict__ dinv, int N)
{
    __shared__ int sh[1024];
    const int tid = threadIdx.x;
    const int chunk = (N + 1023) >> 10;
    int loc[16];
    const int base = tid * chunk;
    int sum = 0;
    for (int c = 0; c < chunk; ++c) {
        int i = base + c;
        int v = (i < N) ? cnt[i] : 0;
        loc[c] = sum;
        sum += v;
    }
    sh[tid] = sum;
    __syncthreads();
    for (int off = 1; off < 1024; off <<= 1) {
        int v = (tid >= off) ? sh[tid - off] : 0;
        __syncthreads();
        sh[tid] += v;
        __syncthreads();
    }
    const int excl = sh[tid] - sum;
    for (int c = 0; c < chunk; ++c) {
        int i = base + c;
        if (i < N) {
            int rs = excl + loc[c];
            row_start[i] = rs;
            cursor[i] = rs;
            dinv[i] = rsqrtf(1.0f + (float)cnt[i]);
        }
    }
    if (tid == 1023) row_start[N] = sh[1023];
}

// ---------------- MFMA GEMM (R7: PREP folds BN+W+wbias into staging) ----------------
template<int KP, bool F32A, bool FILL, bool PREP>
__global__ __launch_bounds__(256) void k_gemm_mfma(
    const void* __restrict__ Xin, const ushort_t* __restrict__ Wt,
    const float* __restrict__ Wf, const float* __restrict__ g,
    const float* __restrict__ be, const float* __restrict__ sp,
    const float* __restrict__ dinv,
    ushort_t* __restrict__ h2, int N, int Mp, int K, int M, float invN,
    int gx, const int* __restrict__ fsrc, const int* __restrict__ fdst,
    int* __restrict__ fcursor, int* __restrict__ fcsr, int fE)
{
    typedef __attribute__((ext_vector_type(8))) short short8;
    typedef __attribute__((ext_vector_type(4))) float floatx4;
    constexpr int LSTR = KP + 16;
    __shared__ ushort_t Bs[64 * LSTR];
    __shared__ float sm_sc[256];
    __shared__ float sm_off[256];
    __shared__ float red[4][64];
    __shared__ float wb_l[64];

    if (FILL) {
        if ((int)blockIdx.x >= gx) {
            const int fid = ((int)blockIdx.x - gx) * (int)gridDim.y + (int)blockIdx.y;
            const int e = fid * 256 + (int)threadIdx.x;
            if (e < fE) {
                int pos = atomicAdd(&fcursor[fdst[e]], 1);
                fcsr[pos] = fsrc[e];
            }
            return;
        }
    }

    const int tid = threadIdx.x;
    const int wave = tid >> 6, lane = tid & 63;
    const int m = lane & 15, quad = lane >> 4;
    const int i0 = blockIdx.x * 64 + wave * 16;
    const int j0 = blockIdx.y * 64;
    const int ncols = min(64, Mp - j0);
    const int ntiles = ncols >> 4;

    if (PREP) {
        {
            const int kk = tid;
            float sc = 0.f, off = 0.f;
            if (kk < K) {
                float ssum = 0.f, qsum = 0.f;
                #pragma unroll
                for (int r = 0; r < NREP; ++r) {
                    ssum += sp[r * 512 + kk];
                    qsum += sp[r * 512 + 256 + kk];
                }
                float mu = ssum * invN;
                float var = qsum * invN - mu * mu;
                sc = g[kk] * rsqrtf(var + 1e-5f);
                off = be[kk] - mu * sc;
            }
            sm_sc[kk] = sc; sm_off[kk] = off;
        }
        __syncthreads();
        {
            const int jj = tid & 63, kg = tid >> 6;
            const int j = j0 + jj;
            float wpart = 0.f;
            for (int kk = kg; kk < KP; kk += 4) {
                float wv = (kk < K && j < M) ? Wf[(long)kk * M + j] : 0.f;
                Bs[jj * LSTR + kk] = f2bf(sm_sc[kk] * wv);
                wpart += sm_off[kk] * wv;
            }
            red[kg][jj] = wpart;
        }
        __syncthreads();
        if (tid < 64) wb_l[tid] = red[0][tid] + red[1][tid] + red[2][tid] + red[3][tid];
        __syncthreads();
    } else {
        const int cpr = KP / 8;
        const int chunks = ncols * cpr;
        for (int c = tid; c < chunks; c += 256) {
            int jj = c / cpr;
            int kk = (c - jj * cpr) * 8;
            *(short8*)(Bs + jj * LSTR + kk) =
                *(const short8*)(Wt + (long)(j0 + jj) * KP + kk);
        }
        __syncthreads();
    }

    if (i0 >= N) return;

    floatx4 acc[4];
    #pragma unroll
    for (int t = 0; t < 4; ++t) { acc[t].x = 0.f; acc[t].y = 0.f; acc[t].z = 0.f; acc[t].w = 0.f; }

    const int ra = min(i0 + m, N - 1);
    const ushort_t* arow_h = F32A ? nullptr : (const ushort_t*)Xin + (long)ra * KP + quad * 8;
    const float*    arow_f = F32A ? (const float*)Xin + (long)ra * KP + quad * 8 : nullptr;

    #pragma unroll
    for (int k0 = 0; k0 < KP; k0 += 32) {
        short8 av;
        if (F32A) {
            float4 f0 = *(const float4*)(arow_f + k0);
            float4 f1 = *(const float4*)(arow_f + k0 + 4);
            av[0] = (short)f2bf(f0.x); av[1] = (short)f2bf(f0.y);
            av[2] = (short)f2bf(f0.z); av[3] = (short)f2bf(f0.w);
            av[4] = (short)f2bf(f1.x); av[5] = (short)f2bf(f1.y);
            av[6] = (short)f2bf(f1.z); av[7] = (short)f2bf(f1.w);
        } else {
            av = *(const short8*)(arow_h + k0);
        }
        #pragma unroll
        for (int t = 0; t < 4; ++t) {
            if (t < ntiles) {
                short8 bv = *(const short8*)(Bs + (t * 16 + m) * LSTR + k0 + quad * 8);
                acc[t] = __builtin_amdgcn_mfma_f32_16x16x32_bf16(av, bv, acc[t], 0, 0, 0);
            }
        }
    }

    #pragma unroll
    for (int t = 0; t < 4; ++t) {
        if (t < ntiles) {
            int j = j0 + t * 16 + m;
            float wb = PREP ? wb_l[t * 16 + m] : 0.0f;   // layer-0 wbias == 0
            #pragma unroll
            for (int r = 0; r < 4; ++r) {
                int i = i0 + quad * 4 + r;
                if (i < N) h2[(long)i * Mp + j] = f2bf((acc[t][r] + wb) * dinv[i]);
            }
        }
    }
}

// ---------------- aggregation: LDS-staged indices + bias, 8-deep gather pipeline ----------------
#define ACC8(W) \
    acc[0] += bf2f((ushort_t)((W).x & 0xffff)); acc[1] += bf2f((ushort_t)((W).x >> 16)); \
    acc[2] += bf2f((ushort_t)((W).y & 0xffff)); acc[3] += bf2f((ushort_t)((W).y >> 16)); \
    acc[4] += bf2f((ushort_t)((W).z & 0xffff)); acc[5] += bf2f((ushort_t)((W).z >> 16)); \
    acc[6] += bf2f((ushort_t)((W).w & 0xffff)); acc[7] += bf2f((ushort_t)((W).w >> 16));

__global__ __launch_bounds__(256) void k_agg(
    const int* __restrict__ row_start, const int* __restrict__ csr_src,
    const ushort_t* __restrict__ h2, int hs,
    const float* __restrict__ dinv, const float* __restrict__ b,
    ushort_t* __restrict__ tmpb, int ts,
    float* __restrict__ sp,
    int N, int M, int Q, ull_t magic, uint_t sh)
{
    __shared__ float s_s[256];
    __shared__ float s_q[256];
    __shared__ float s_b[256];
    __shared__ int s_idx[IDXCAP];
    const int tid = threadIdx.x;
    s_s[tid] = 0.f;
    s_q[tid] = 0.f;
    s_b[tid] = (tid < M) ? b[tid] : 0.f;

    // block's contiguous edge range -> LDS
    const uint_t g0 = blockIdx.x * 256u;
    uint_t i0b = (uint_t)(((ull_t)g0 * magic) >> sh);
    uint_t i1b = (uint_t)(((ull_t)(g0 + 255u) * magic) >> sh);
    if (i0b >= (uint_t)N) i0b = N - 1;
    if (i1b >= (uint_t)N) i1b = N - 1;
    const int eb0 = row_start[i0b];
    const int ecnt = row_start[i1b + 1] - eb0;
    const bool staged = (ecnt <= IDXCAP);
    if (staged) {
        for (int k2 = tid; k2 < ecnt; k2 += 256) s_idx[k2] = csr_src[eb0 + k2];
    }
    __syncthreads();

    const uint_t g = g0 + tid;
    const uint_t i = (uint_t)(((ull_t)g * magic) >> sh);
    const int jp = (int)(g - i * Q);
    const int j0 = jp * 8;
    float vals[8];
    bool active = false;

    if (i < (uint_t)N) {
        if (j0 >= M) {
            *(uint4*)(tmpb + (long)i * ts + j0) = make_uint4(0u, 0u, 0u, 0u);
        } else {
            active = true;
            const int s0 = row_start[i];
            const int s1 = row_start[i + 1];
            const ushort_t* hp = h2 + j0;
            float acc[8];
            {
                uint4 v = *(const uint4*)(hp + (long)i * hs);
                acc[0] = bf2f((ushort_t)(v.x & 0xffff)); acc[1] = bf2f((ushort_t)(v.x >> 16));
                acc[2] = bf2f((ushort_t)(v.y & 0xffff)); acc[3] = bf2f((ushort_t)(v.y >> 16));
                acc[4] = bf2f((ushort_t)(v.z & 0xffff)); acc[5] = bf2f((ushort_t)(v.z >> 16));
                acc[6] = bf2f((ushort_t)(v.w & 0xffff)); acc[7] = bf2f((ushort_t)(v.w >> 16));
            }
            int e = s0;
            if (staged) {
                const int lb = s0 - eb0;
                const int le = s1 - eb0;
                int k2 = lb;
                for (; k2 + 7 < le; k2 += 8) {
                    int n[8];
                    #pragma unroll
                    for (int u = 0; u < 8; ++u) n[u] = s_idx[k2 + u];
                    uint4 w[8];
                    #pragma unroll
                    for (int u = 0; u < 8; ++u)
                        w[u] = *(const uint4*)(hp + (long)n[u] * hs);
                    #pragma unroll
                    for (int u = 0; u < 8; ++u) { ACC8(w[u]) }
                }
                if (k2 + 3 < le) {
                    int n[4];
                    #pragma unroll
                    for (int u = 0; u < 4; ++u) n[u] = s_idx[k2 + u];
                    uint4 w[4];
                    #pragma unroll
                    for (int u = 0; u < 4; ++u)
                        w[u] = *(const uint4*)(hp + (long)n[u] * hs);
                    #pragma unroll
                    for (int u = 0; u < 4; ++u) { ACC8(w[u]) }
                    k2 += 4;
                }
                for (; k2 < le; ++k2) {
                    uint4 w = *(const uint4*)(hp + (long)s_idx[k2] * hs);
                    ACC8(w)
                }
            } else {
                for (; e + 7 < s1; e += 8) {
                    uint4 w[8];
                    #pragma unroll
                    for (int u = 0; u < 8; ++u)
                        w[u] = *(const uint4*)(hp + (long)csr_src[e + u] * hs);
                    #pragma unroll
                    for (int u = 0; u < 8; ++u) { ACC8(w[u]) }
                }
                for (; e < s1; ++e) {
                    uint4 w = *(const uint4*)(hp + (long)csr_src[e] * hs);
                    ACC8(w)
                }
            }
            const float di = dinv[i];
            ushort_t r[8];
            #pragma unroll
            for (int u = 0; u < 8; ++u) {
                float v = (j0 + u < M) ? fmaxf(acc[u] * di + s_b[j0 + u], 0.f) : 0.f;
                vals[u] = v;
                r[u] = f2bf(v);
            }
            uint4 pk;
            pk.x = (uint_t)r[0] | ((uint_t)r[1] << 16);
            pk.y = (uint_t)r[2] | ((uint_t)r[3] << 16);
            pk.z = (uint_t)r[4] | ((uint_t)r[5] << 16);
            pk.w = (uint_t)r[6] | ((uint_t)r[7] << 16);
            *(uint4*)(tmpb + (long)i * ts + j0) = pk;
        }
    }

    if (active) {
        #pragma unroll
        for (int u = 0; u < 8; ++u) {
            atomicAdd(&s_s[j0 + u], vals[u]);
            atomicAdd(&s_q[j0 + u], vals[u] * vals[u]);
        }
    }
    __syncthreads();
    float* rep = sp + ((int)blockIdx.x & (NREP - 1)) * 512;
    if (tid < ts && (s_s[tid] != 0.f || s_q[tid] != 0.f)) {
        unsafeAtomicAdd(&rep[tid], s_s[tid]);
        unsafeAtomicAdd(&rep[tid + 256], s_q[tid]);
    }
}

// ---------------- final layer: LDS-staged indices + gather + log_softmax ----------------
__global__ __launch_bounds__(256) void k_agg_final(
    const int* __restrict__ row_start, const int* __restrict__ csr_src,
    const ushort_t* __restrict__ h2, const float* __restrict__ dinv,
    const float* __restrict__ b, float* __restrict__ out, int N, int M)
{
    __shared__ int s_idx[FIDXCAP];
    const int tid = threadIdx.x;
    const int x = tid & 15;
    const int r = tid >> 4;
    const int i = blockIdx.x * 16 + r;

    int i0b = blockIdx.x * 16;
    int i1b = min(i0b + 15, N - 1);
    if (i0b >= N) i0b = N - 1;
    const int eb0 = row_start[i0b];
    const int ecnt = row_start[i1b + 1] - eb0;
    const bool staged = (ecnt <= FIDXCAP);
    if (staged) {
        for (int k2 = tid; k2 < ecnt; k2 += 256) s_idx[k2] = csr_src[eb0 + k2];
    }
    __syncthreads();
    if (i >= N) return;

    const int j0 = 2 * x, j1 = j0 + 1;
    uint_t v = *(const uint_t*)(h2 + (long)i * 32 + j0);
    float a0 = bf2f((ushort_t)(v & 0xffff));
    float a1 = bf2f((ushort_t)(v >> 16));
    const int s0 = row_start[i];
    const int s1 = row_start[i + 1];
    if (staged) {
        int k2 = s0 - eb0;
        const int le = s1 - eb0;
        for (; k2 + 3 < le; k2 += 4) {
            int n[4];
            #pragma unroll
            for (int u = 0; u < 4; ++u) n[u] = s_idx[k2 + u];
            uint_t w[4];
            #pragma unroll
            for (int u = 0; u < 4; ++u)
                w[u] = *(const uint_t*)(h2 + (long)n[u] * 32 + j0);
            #pragma unroll
            for (int u = 0; u < 4; ++u) {
                a0 += bf2f((ushort_t)(w[u] & 0xffff));
                a1 += bf2f((ushort_t)(w[u] >> 16));
            }
        }
        for (; k2 < le; ++k2) {
            uint_t w = *(const uint_t*)(h2 + (long)s_idx[k2] * 32 + j0);
            a0 += bf2f((ushort_t)(w & 0xffff)); a1 += bf2f((ushort_t)(w >> 16));
        }
    } else {
        for (int e = s0; e < s1; ++e) {
            uint_t w = *(const uint_t*)(h2 + (long)csr_src[e] * 32 + j0);
            a0 += bf2f((ushort_t)(w & 0xffff)); a1 += bf2f((ushort_t)(w >> 16));
        }
    }
    const float di = dinv[i];
    float r0 = (j0 < M) ? (a0 * di + b[j0]) : -INFINITY;
    float r1 = (j1 < M) ? (a1 * di + b[j1]) : -INFINITY;
    float m = fmaxf(r0, r1);
    #pragma unroll
    for (int msk = 1; msk < 16; msk <<= 1) m = fmaxf(m, __shfl_xor(m, msk, 16));
    float s = ((j0 < M) ? expf(r0 - m) : 0.f) + ((j1 < M) ? expf(r1 - m) : 0.f);
    #pragma unroll
    for (int msk = 1; msk < 16; msk <<= 1) s += __shfl_xor(s, msk, 16);
    const float l = logf(s) + m;
    if (j0 < M) out[(long)i * M + j0] = r0 - l;
    if (j1 < M) out[(long)i * M + j1] = r1 - l;
}

// ---------------- launch ----------------

static inline int pad16(int v) { return (v + 15) & ~15; }
static inline int pad32(int v) { return (v + 31) & ~31; }

extern "C" void kernel_launch(void* const* d_in, const int* in_sizes, int n_in,
                              void* d_out, int out_size, void* d_ws, size_t ws_size,
                              hipStream_t stream)
{
    const int dims[6] = {256, 220, 150, 100, 60, 17};
    const int N = in_sizes[0] / dims[0];      // 10000
    const int E = in_sizes[1] / 2;            // 320000

    const float* x  = (const float*)d_in[0];
    const int* ei   = (const int*)d_in[1];
    const int* srcv = ei;
    const int* dstv = ei + E;
    const float* Wl[5], *bl[5];
    for (int l = 0; l < 5; ++l) {
        Wl[l] = (const float*)d_in[2 + 2 * l];
        bl[l] = (const float*)d_in[3 + 2 * l];
    }
    const float* gl[4], *bel[4];
    for (int l = 0; l < 4; ++l) {
        gl[l]  = (const float*)d_in[12 + 2 * l];
        bel[l] = (const float*)d_in[13 + 2 * l];
    }
    float* out = (float*)d_out;

    // ---- workspace layout ----
    char* w = (char*)d_ws;
    const long NB  = ((long)N * 4 + 255) & ~255L;
    const long NB1 = ((long)(N + 1) * 4 + 255) & ~255L;
    const long EB  = ((long)E * 4 + 255) & ~255L;
    const long FBB = ((long)N * 224 * 2 + 255) & ~255L;
    const long WTB = ((long)224 * 256 * 2 + 255) & ~255L;
    const long STB = (long)4 * NREP * 512 * 4;

    long o = 0;
    float* dinv      = (float*)(w + o);  o += NB;
    float* stats     = (float*)(w + o);  o += STB;
    int*   cnt       = (int*)(w + o);    o += NB;
    int*   row_start = (int*)(w + o);    o += NB1;
    int*   cursor    = (int*)(w + o);    o += NB;
    int*   csr_src   = (int*)(w + o);    o += EB;
    ushort_t* Wt     = (ushort_t*)(w + o); o += WTB;
    ushort_t* h2     = (ushort_t*)(w + o); o += FBB;
    ushort_t* tmpb   = (ushort_t*)(w + o); o += FBB;

    const int eBlk = (E + 255) / 256;
    const float invN = 1.0f / (float)N;

    k_init<<<(N + 255) / 256, 256, 0, stream>>>(cnt, stats, N);
    k_hist_prep0<<<eBlk + 56, 256, 0, stream>>>(dstv, cnt, E, eBlk, Wl[0], Wt);
    k_scan<<<1, 1024, 0, stream>>>(cnt, row_start, cursor, dinv, N);

    for (int l = 0; l < 5; ++l) {
        const int K  = dims[l];
        const int M  = dims[l + 1];
        const int Kp = pad32(K);
        const int Mp = pad16(M);
        const int ts = (l < 4) ? pad32(M) : 32;

        dim3 gg((N + 63) / 64, (Mp + 63) / 64);
        if (l == 0) {
            const int fx = (eBlk + (int)gg.y - 1) / (int)gg.y;
            dim3 gg0(gg.x + fx, gg.y);
            k_gemm_mfma<256, true, true, false><<<gg0, 256, 0, stream>>>(
                x, Wt, nullptr, nullptr, nullptr, nullptr,
                dinv, h2, N, Mp, K, M, invN,
                (int)gg.x, srcv, dstv, cursor, csr_src, E);
        } else {
            const float* sp = stats + (long)(l - 1) * NREP * 512;
            switch (Kp) {
                case 224: k_gemm_mfma<224, false, false, true><<<gg, 256, 0, stream>>>(
                    tmpb, nullptr, Wl[l], gl[l - 1], bel[l - 1], sp,
                    dinv, h2, N, Mp, K, M, invN, 0, nullptr, nullptr, nullptr, nullptr, 0); break;
                case 160: k_gemm_mfma<160, false, false, true><<<gg, 256, 0, stream>>>(
                    tmpb, nullptr, Wl[l], gl[l - 1], bel[l - 1], sp,
                    dinv, h2, N, Mp, K, M, invN, 0, nullptr, nullptr, nullptr, nullptr, 0); break;
                case 128: k_gemm_mfma<128, false, false, true><<<gg, 256, 0, stream>>>(
                    tmpb, nullptr, Wl[l], gl[l - 1], bel[l - 1], sp,
                    dinv, h2, N, Mp, K, M, invN, 0, nullptr, nullptr, nullptr, nullptr, 0); break;
                case  64: k_gemm_mfma< 64, false, false, true><<<gg, 256, 0, stream>>>(
                    tmpb, nullptr, Wl[l], gl[l - 1], bel[l - 1], sp,
                    dinv, h2, N, Mp, K, M, invN, 0, nullptr, nullptr, nullptr, nullptr, 0); break;
            }
        }

        if (l < 4) {
            const int Q = ts / 8;
            uint_t shmt = 0;
            while ((1u << shmt) < (uint_t)Q) ++shmt;
            shmt += 32;
            const ull_t magic = ((1ULL << shmt) + Q - 1) / (ull_t)Q;
            const long total = (long)N * Q;
            k_agg<<<(int)((total + 255) / 256), 256, 0, stream>>>(
                row_start, csr_src, h2, Mp, dinv, bl[l], tmpb, ts,
                stats + (long)l * NREP * 512,
                N, M, Q, magic, shmt);
        } else {
            k_agg_final<<<(N + 15) / 16, 256, 0, stream>>>(
                row_start, csr_src, h2, dinv, bl[l], out, N, M);
        }
    }
}